// Round 2
// baseline (829.824 us; speedup 1.0000x reference)
//
#include <hip/hip_runtime.h>
#include <cstddef>

static constexpr int CB = 64;    // batch
static constexpr int CN = 512;   // nodes
static constexpr int CD = 256;   // node model dim
static constexpr int CE = 128;   // edge model dim
static constexpr int CIT = 20;   // sinkhorn iterations

typedef _Float16 half_t;
typedef __attribute__((ext_vector_type(8))) _Float16 v8h;
typedef __attribute__((ext_vector_type(4))) float v4f;

// ---------------------------------------------------------------------------
// k0: block 0 detects the storage layout of the bool mask (same logic that
// passed in R1); block 1 zeroes the per-batch barrier counters.
// flag: 0=int32, 1=uint8(bool), 2=float32, 3=int64
// ---------------------------------------------------------------------------
__global__ __launch_bounds__(512) void k0_init(const void* __restrict__ mask,
                                               int* __restrict__ bar,
                                               int* __restrict__ flag) {
  const int tid = threadIdx.x;
  if (blockIdx.x == 1) {
#pragma unroll
    for (int k = 0; k < 4; ++k) bar[tid * 4 + k] = 0;
    return;
  }
  __shared__ int cnt[5];
  if (tid < 5) cnt[tid] = 0;
  __syncthreads();
  const unsigned char* p = (const unsigned char*)mask;
  int l0 = 0, l1 = 0, l2 = 0, l3 = 0, l4 = 0;
  const int base = tid * 64;
  for (int k = 0; k < 64; ++k) {
    const int off = base + k;
    if (p[off]) {
      const int m4 = off & 3;
      if (m4 == 1) l1++;
      else if (m4 == 2) l2++;
      else if (m4 == 3) l3++;
      else if ((off & 7) == 4) l4++;
      else l0++;
    }
  }
  if (l0) atomicAdd(&cnt[0], 1);
  if (l1) atomicAdd(&cnt[1], 1);
  if (l2) atomicAdd(&cnt[2], 1);
  if (l3) atomicAdd(&cnt[3], 1);
  if (l4) atomicAdd(&cnt[4], 1);
  __syncthreads();
  if (tid == 0) {
    int f;
    if (cnt[1]) f = 1;
    else if (cnt[2] || cnt[3]) f = 2;
    else if (cnt[4]) f = 0;
    else if (cnt[0]) f = 3;
    else f = 1;
    *flag = f;
  }
}

// ---------------------------------------------------------------------------
// prep_gemm: out[row, e] fp16, rows = b*N+i (M=32768), K=D=256, Ncols=E=128.
// MODE 0: x = out_emb + pos,       out = fp16((x @ W) * w_aff)
// MODE 1: x = mask ? pad : in_emb, out = fp16( x @ W )
// ---------------------------------------------------------------------------
template <int MODE>
__global__ __launch_bounds__(256) void prep_gemm(
    const float* __restrict__ X, const float* __restrict__ extra,
    const void* __restrict__ maskp, const int* __restrict__ flagp,
    const float* __restrict__ W, const float* __restrict__ w_aff,
    half_t* __restrict__ out) {
  __shared__ float Xs[64][65];
  __shared__ alignas(16) float Ws[64][CE];
  const int tid = threadIdx.x;
  const int row0 = blockIdx.x * 64;
  const int tx = tid & 15, ty = tid >> 4;
  const int flag = (MODE == 1) ? *flagp : 0;
  float acc[4][8];
#pragma unroll
  for (int a = 0; a < 4; ++a)
#pragma unroll
    for (int c = 0; c < 8; ++c) acc[a][c] = 0.0f;

  for (int kc = 0; kc < CD; kc += 64) {
    {
      const int lk = tid & 15;
      const int rp = tid >> 4;
#pragma unroll
      for (int pass = 0; pass < 4; ++pass) {
        const int r = pass * 16 + rp;
        const int row = row0 + r;
        const int i = row & (CN - 1);
        const int d = kc + lk * 4;
        float4 x4;
        if (MODE == 0) {
          x4 = *(const float4*)&X[(size_t)row * CD + d];
          const float4 p4 = *(const float4*)&extra[(size_t)i * CD + d];
          x4.x += p4.x; x4.y += p4.y; x4.z += p4.z; x4.w += p4.w;
        } else {
          bool m;
          if (flag == 1)      m = ((const unsigned char*)maskp)[row] != 0;
          else if (flag == 2) m = ((const float*)maskp)[row] != 0.0f;
          else if (flag == 3) m = ((const long long*)maskp)[row] != 0;
          else                m = ((const int*)maskp)[row] != 0;
          if (m) x4 = *(const float4*)&extra[d];
          else   x4 = *(const float4*)&X[(size_t)row * CD + d];
        }
        Xs[r][lk * 4 + 0] = x4.x; Xs[r][lk * 4 + 1] = x4.y;
        Xs[r][lk * 4 + 2] = x4.z; Xs[r][lk * 4 + 3] = x4.w;
      }
    }
    {
      const int cv = tid & 31;
      const int kr = tid >> 5;
#pragma unroll
      for (int pass = 0; pass < 8; ++pass) {
        const int kk = pass * 8 + kr;
        *(float4*)&Ws[kk][cv * 4] = *(const float4*)&W[(size_t)(kc + kk) * CE + cv * 4];
      }
    }
    __syncthreads();
#pragma unroll 4
    for (int kk = 0; kk < 64; ++kk) {
      float xa[4];
#pragma unroll
      for (int a = 0; a < 4; ++a) xa[a] = Xs[ty * 4 + a][kk];
      const float4 wb0 = *(const float4*)&Ws[kk][tx * 8];
      const float4 wb1 = *(const float4*)&Ws[kk][tx * 8 + 4];
      const float wb[8] = {wb0.x, wb0.y, wb0.z, wb0.w, wb1.x, wb1.y, wb1.z, wb1.w};
#pragma unroll
      for (int a = 0; a < 4; ++a)
#pragma unroll
        for (int c = 0; c < 8; ++c) acc[a][c] += xa[a] * wb[c];
    }
    __syncthreads();
  }
  float wa[8];
  if (MODE == 0) {
#pragma unroll
    for (int c = 0; c < 8; ++c) wa[c] = w_aff[tx * 8 + c];
  }
#pragma unroll
  for (int a = 0; a < 4; ++a) {
    const int row = row0 + ty * 4 + a;
    v8h hv;
#pragma unroll
    for (int c = 0; c < 8; ++c) {
      const float o = (MODE == 0) ? acc[a][c] * wa[c] : acc[a][c];
      hv[c] = (half_t)o;
    }
    *(v8h*)&out[(size_t)row * CE + tx * 8] = hv;
  }
}

// ---------------------------------------------------------------------------
// Per-batch barrier among the 4 slab-blocks of a batch (all blocks resident:
// grid = 256 = CU count, occupancy floor 1/CU => capacity >= grid).
// ---------------------------------------------------------------------------
__device__ __forceinline__ void batch_barrier(int* __restrict__ bar, int b, int gen4) {
  __syncthreads();
  if (threadIdx.x == 0) {
    __hip_atomic_fetch_add(&bar[b * 32], 1, __ATOMIC_RELEASE, __HIP_MEMORY_SCOPE_AGENT);
    while (__hip_atomic_load(&bar[b * 32], __ATOMIC_ACQUIRE, __HIP_MEMORY_SCOPE_AGENT) < gen4)
      __builtin_amdgcn_s_sleep(2);
  }
  __syncthreads();
}

// ---------------------------------------------------------------------------
// fused: per block = (batch b, slab of 128 rows):
//   1) E = exp(A·B^T + b_aff) via fp16 MFMA, written fp32 to d_out
//   2) init sweep: rs (local) + cs column-partials -> barrier -> csinv
//   3) 20 iters: ONE sweep computes u_i per row (butterfly) and immediately
//      accumulates column partials with E in registers -> barrier -> v
//   4) finalize in place: P = E * u_i * v_j * (0.5*csinv_j + 0.5*rinv_i)
// ---------------------------------------------------------------------------
__global__ __launch_bounds__(256) void fused(
    const half_t* __restrict__ A_h, const half_t* __restrict__ B_h,
    const float* __restrict__ baff, float* __restrict__ Eout,
    float* __restrict__ part, int* __restrict__ bar) {
  __shared__ alignas(16) char smem[65536];
  half_t* Als = (half_t*)smem;                    // [32][64][8] = 32 KB (GEMM)
  half_t* Bls = (half_t*)(smem + 32768);          // [32][64][8] = 32 KB (GEMM)
  float* comb  = (float*)smem;                    // [4][2][512] = 16 KB (sinkhorn)
  float* w1    = (float*)(smem + 16384);          // [512] 0.5*v*csinv
  float* w2    = (float*)(smem + 18432);          // [512] v
  float* q2    = (float*)(smem + 20480);          // [512] 0.5*v
  float* csinv = (float*)(smem + 22528);          // [512]
  float* rinv  = (float*)(smem + 24576);          // [128]
  float* uarr  = (float*)(smem + 25088);          // [128]

  const int tid = threadIdx.x;
  const int wv = tid >> 6, ln = tid & 63;
  const int b = blockIdx.x & 63;
  const int slab = blockIdx.x >> 6;
  const int i0 = slab * 128;
  const float bb = *baff;

  // ---- 1) slab GEMM: aff[i0..i0+128) x [0..512) , K=128, fp16 MFMA ----
  // stage A slab in fragment order: combo c=(rt,ki), lane l holds
  // A[i0+rt*16+(l&15)][ki*32+(l>>4)*8 .. +8)
#pragma unroll
  for (int cc = 0; cc < 8; ++cc) {
    const int c = wv * 8 + cc;
    const int rt = c >> 2, ki = c & 3;
    const int row = i0 + rt * 16 + (ln & 15);
    const int e = ki * 32 + (ln >> 4) * 8;
    *(v8h*)&Als[(size_t)(c * 64 + ln) * 8] =
        *(const v8h*)&A_h[((size_t)b * CN + row) * CE + e];
  }
  for (int p = 0; p < 4; ++p) {      // 4 col panels of 128
    __syncthreads();
#pragma unroll
    for (int cc = 0; cc < 8; ++cc) {
      const int c = wv * 8 + cc;
      const int ct = c >> 2, ki = c & 3;
      const int col = p * 128 + ct * 16 + (ln & 15);
      const int e = ki * 32 + (ln >> 4) * 8;
      *(v8h*)&Bls[(size_t)(c * 64 + ln) * 8] =
          *(const v8h*)&B_h[((size_t)b * CN + col) * CE + e];
    }
    __syncthreads();
    v4f acc[2][8] = {};
#pragma unroll
    for (int ki = 0; ki < 4; ++ki) {
      v8h af[2], bf[8];
#pragma unroll
      for (int r = 0; r < 2; ++r)
        af[r] = *(v8h*)&Als[(size_t)((((2 * wv + r) * 4 + ki) * 64) + ln) * 8];
#pragma unroll
      for (int ct = 0; ct < 8; ++ct)
        bf[ct] = *(v8h*)&Bls[(size_t)(((ct * 4 + ki) * 64) + ln) * 8];
#pragma unroll
      for (int r = 0; r < 2; ++r)
#pragma unroll
        for (int ct = 0; ct < 8; ++ct)
          acc[r][ct] = __builtin_amdgcn_mfma_f32_16x16x32_f16(af[r], bf[ct], acc[r][ct], 0, 0, 0);
    }
    // epilogue: exp + store fp32 E to d_out
#pragma unroll
    for (int r = 0; r < 2; ++r)
#pragma unroll
      for (int ct = 0; ct < 8; ++ct) {
        const int j = p * 128 + ct * 16 + (ln & 15);
#pragma unroll
        for (int g = 0; g < 4; ++g) {
          const int i = i0 + (2 * wv + r) * 16 + (ln >> 4) * 4 + g;
          Eout[((size_t)b * CN + i) * CN + j] = __expf(acc[r][ct][g] + bb);
        }
      }
  }
  __syncthreads();   // GEMM done; smem low region now reused by sinkhorn

  float* Eslab = &Eout[((size_t)b * CN + i0) * CN];  // local rows [0,128)
  int gen = 0;

  // ---- 2) init sweep: row sums (local) + column partial sums ----
  {
    float s1[8];
#pragma unroll
    for (int c = 0; c < 8; ++c) s1[c] = 0.0f;
    for (int rr = 0; rr < 32; ++rr) {
      const int i = wv * 32 + rr;
      const float* row = &Eslab[(size_t)i * CN + ln * 8];
      const float4 e0 = *(const float4*)&row[0];
      const float4 e1 = *(const float4*)&row[4];
      const float ea[8] = {e0.x, e0.y, e0.z, e0.w, e1.x, e1.y, e1.z, e1.w};
      float d = 0.0f;
#pragma unroll
      for (int c = 0; c < 8; ++c) { d += ea[c]; s1[c] += ea[c]; }
#pragma unroll
      for (int m = 1; m < 64; m <<= 1) d += __shfl_xor(d, m);
      if (ln == 0) rinv[i] = 1.0f / d;
    }
    *(float4*)&comb[(size_t)(wv * 2 + 0) * 512 + ln * 8] = make_float4(s1[0], s1[1], s1[2], s1[3]);
    *(float4*)&comb[(size_t)(wv * 2 + 0) * 512 + ln * 8 + 4] = make_float4(s1[4], s1[5], s1[6], s1[7]);
    __syncthreads();
    // thread t owns cols 2t,2t+1 -> write global partials
    const int slot = gen & 1;
    float S[2];
#pragma unroll
    for (int h = 0; h < 2; ++h) {
      const int c = 2 * tid + h;
      S[h] = comb[0 * 1024 + c] + comb[2 * 512 + c] + comb[4 * 512 + c] + comb[6 * 512 + c];
    }
    *(float2*)&part[((((size_t)slot * 64 + b) * 4 + slab) * 2 + 0) * 512 + 2 * tid] =
        make_float2(S[0], S[1]);
    ++gen;
    batch_barrier(bar, b, 4 * gen);
    // csinv + initial weights (v = 1)
#pragma unroll
    for (int h = 0; h < 2; ++h) {
      const int c = 2 * tid + h;
      float cs = 0.0f;
#pragma unroll
      for (int s = 0; s < 4; ++s)
        cs += part[((((size_t)slot * 64 + b) * 4 + s) * 2 + 0) * 512 + c];
      const float ci = 1.0f / cs;
      csinv[c] = ci;
      w1[c] = 0.5f * ci;   // 0.5 * v * csinv, v=1
      w2[c] = 1.0f;        // v
      q2[c] = 0.5f;        // 0.5 * v
    }
  }

  // ---- 3) 20 fused u+v sweeps ----
  for (int t = 0; t < CIT; ++t) {
    __syncthreads();   // w1/w2 ready; comb safe to rewrite
    float pw1[8], pw2[8];
    {
      const float4 a0 = *(const float4*)&w1[ln * 8];
      const float4 a1 = *(const float4*)&w1[ln * 8 + 4];
      const float4 b0 = *(const float4*)&w2[ln * 8];
      const float4 b1 = *(const float4*)&w2[ln * 8 + 4];
      pw1[0] = a0.x; pw1[1] = a0.y; pw1[2] = a0.z; pw1[3] = a0.w;
      pw1[4] = a1.x; pw1[5] = a1.y; pw1[6] = a1.z; pw1[7] = a1.w;
      pw2[0] = b0.x; pw2[1] = b0.y; pw2[2] = b0.z; pw2[3] = b0.w;
      pw2[4] = b1.x; pw2[5] = b1.y; pw2[6] = b1.z; pw2[7] = b1.w;
    }
    float s1[8], s2[8];
#pragma unroll
    for (int c = 0; c < 8; ++c) { s1[c] = 0.0f; s2[c] = 0.0f; }
    for (int rr = 0; rr < 32; ++rr) {
      const int i = wv * 32 + rr;
      const float* row = &Eslab[(size_t)i * CN + ln * 8];
      const float4 e0 = *(const float4*)&row[0];
      const float4 e1 = *(const float4*)&row[4];
      const float ea[8] = {e0.x, e0.y, e0.z, e0.w, e1.x, e1.y, e1.z, e1.w};
      float d1 = 0.0f, d2 = 0.0f;
#pragma unroll
      for (int c = 0; c < 8; ++c) { d1 += ea[c] * pw1[c]; d2 += ea[c] * pw2[c]; }
#pragma unroll
      for (int m = 1; m < 64; m <<= 1) { d1 += __shfl_xor(d1, m); d2 += __shfl_xor(d2, m); }
      const float ri = rinv[i];
      const float u = 1.0f / (d1 + 0.5f * ri * d2);
      if (ln == 0) uarr[i] = u;
      const float ub = u * ri;
#pragma unroll
      for (int c = 0; c < 8; ++c) { s1[c] += ea[c] * u; s2[c] += ea[c] * ub; }
    }
    *(float4*)&comb[(size_t)(wv * 2 + 0) * 512 + ln * 8]     = make_float4(s1[0], s1[1], s1[2], s1[3]);
    *(float4*)&comb[(size_t)(wv * 2 + 0) * 512 + ln * 8 + 4] = make_float4(s1[4], s1[5], s1[6], s1[7]);
    *(float4*)&comb[(size_t)(wv * 2 + 1) * 512 + ln * 8]     = make_float4(s2[0], s2[1], s2[2], s2[3]);
    *(float4*)&comb[(size_t)(wv * 2 + 1) * 512 + ln * 8 + 4] = make_float4(s2[4], s2[5], s2[6], s2[7]);
    __syncthreads();
    const int slot = gen & 1;
    float S1[2], S2[2];
#pragma unroll
    for (int h = 0; h < 2; ++h) {
      const int c = 2 * tid + h;
      S1[h] = comb[0 * 512 + c] + comb[2 * 512 + c] + comb[4 * 512 + c] + comb[6 * 512 + c];
      S2[h] = comb[1 * 512 + c] + comb[3 * 512 + c] + comb[5 * 512 + c] + comb[7 * 512 + c];
    }
    *(float2*)&part[((((size_t)slot * 64 + b) * 4 + slab) * 2 + 0) * 512 + 2 * tid] =
        make_float2(S1[0], S1[1]);
    *(float2*)&part[((((size_t)slot * 64 + b) * 4 + slab) * 2 + 1) * 512 + 2 * tid] =
        make_float2(S2[0], S2[1]);
    ++gen;
    batch_barrier(bar, b, 4 * gen);
    // v recompute (redundant per block) + next-iteration weights
#pragma unroll
    for (int h = 0; h < 2; ++h) {
      const int c = 2 * tid + h;
      float T1 = 0.0f, T2 = 0.0f;
#pragma unroll
      for (int s = 0; s < 4; ++s) {
        T1 += part[((((size_t)slot * 64 + b) * 4 + s) * 2 + 0) * 512 + c];
        T2 += part[((((size_t)slot * 64 + b) * 4 + s) * 2 + 1) * 512 + c];
      }
      const float ci = csinv[c];
      const float vv = 1.0f / (0.5f * (ci * T1 + T2));
      w1[c] = 0.5f * vv * ci;
      w2[c] = vv;
      q2[c] = 0.5f * vv;
    }
  }

  // ---- 4) finalize in place ----
  __syncthreads();
  float fq1[8], fq2[8];
  {
    const float4 a0 = *(const float4*)&w1[ln * 8];
    const float4 a1 = *(const float4*)&w1[ln * 8 + 4];
    const float4 b0 = *(const float4*)&q2[ln * 8];
    const float4 b1 = *(const float4*)&q2[ln * 8 + 4];
    fq1[0] = a0.x; fq1[1] = a0.y; fq1[2] = a0.z; fq1[3] = a0.w;
    fq1[4] = a1.x; fq1[5] = a1.y; fq1[6] = a1.z; fq1[7] = a1.w;
    fq2[0] = b0.x; fq2[1] = b0.y; fq2[2] = b0.z; fq2[3] = b0.w;
    fq2[4] = b1.x; fq2[5] = b1.y; fq2[6] = b1.z; fq2[7] = b1.w;
  }
  for (int rr = 0; rr < 32; ++rr) {
    const int i = wv * 32 + rr;
    const float u = uarr[i];
    const float t2 = u * rinv[i];
    float* row = &Eslab[(size_t)i * CN + ln * 8];
    const float4 e0 = *(const float4*)&row[0];
    const float4 e1 = *(const float4*)&row[4];
    float4 o0, o1;
    o0.x = e0.x * (u * fq1[0] + t2 * fq2[0]);
    o0.y = e0.y * (u * fq1[1] + t2 * fq2[1]);
    o0.z = e0.z * (u * fq1[2] + t2 * fq2[2]);
    o0.w = e0.w * (u * fq1[3] + t2 * fq2[3]);
    o1.x = e1.x * (u * fq1[4] + t2 * fq2[4]);
    o1.y = e1.y * (u * fq1[5] + t2 * fq2[5]);
    o1.z = e1.z * (u * fq1[6] + t2 * fq2[6]);
    o1.w = e1.w * (u * fq1[7] + t2 * fq2[7]);
    *(float4*)&row[0] = o0;
    *(float4*)&row[4] = o1;
  }
}

// ---------------------------------------------------------------------------
extern "C" void kernel_launch(void* const* d_in, const int* in_sizes, int n_in,
                              void* d_out, int out_size, void* d_ws, size_t ws_size,
                              hipStream_t stream) {
  const float* in_emb  = (const float*)d_in[0];
  const void*  mask    = d_in[1];
  const float* out_emb = (const float*)d_in[2];
  const float* pad     = (const float*)d_in[3];
  const float* pos     = (const float*)d_in[4];
  const float* W_a     = (const float*)d_in[5];
  const float* W_b     = (const float*)d_in[6];
  const float* w_aff   = (const float*)d_in[7];
  const float* b_aff   = (const float*)d_in[8];
  float* P = (float*)d_out;                       // holds E then P in place

  char* ws = (char*)d_ws;
  half_t* A_h  = (half_t*)ws;                                    // 8 MB
  half_t* Bm_h = (half_t*)(ws + (size_t)8 * 1024 * 1024);        // 8 MB
  float*  part = (float*)(ws + (size_t)16 * 1024 * 1024);        // 2 MB
  int*    bar  = (int*)(ws + (size_t)18 * 1024 * 1024);          // 8 KB
  int*    flag = (int*)(ws + (size_t)18 * 1024 * 1024 + 8192);

  k0_init<<<dim3(2), dim3(512), 0, stream>>>(mask, bar, flag);
  prep_gemm<0><<<dim3(CB * CN / 64), dim3(256), 0, stream>>>(
      out_emb, pos, nullptr, flag, W_a, w_aff, A_h);
  prep_gemm<1><<<dim3(CB * CN / 64), dim3(256), 0, stream>>>(
      in_emb, pad, mask, flag, W_b, nullptr, Bm_h);
  fused<<<dim3(256), dim3(256), 0, stream>>>(A_h, Bm_h, b_aff, P, part, bar);
}

// Round 3
// 457.354 us; speedup vs baseline: 1.8144x; 1.8144x over previous
//
#include <hip/hip_runtime.h>
#include <cstddef>

static constexpr int CB = 64;    // batch
static constexpr int CN = 512;   // nodes
static constexpr int CD = 256;   // node model dim
static constexpr int CE = 128;   // edge model dim
static constexpr int CIT = 20;   // sinkhorn iterations

typedef _Float16 half_t;
typedef __attribute__((ext_vector_type(8))) _Float16 v8h;
typedef __attribute__((ext_vector_type(4))) _Float16 v4h;
typedef __attribute__((ext_vector_type(4))) float v4f;

// ---------------------------------------------------------------------------
// k0: block 0 detects the storage layout of the bool mask; block 1 zeroes the
// per-batch barrier counters. flag: 0=int32, 1=uint8(bool), 2=float32, 3=int64
// ---------------------------------------------------------------------------
__global__ __launch_bounds__(512) void k0_init(const void* __restrict__ mask,
                                               int* __restrict__ bar,
                                               int* __restrict__ flag) {
  const int tid = threadIdx.x;
  if (blockIdx.x == 1) {
#pragma unroll
    for (int k = 0; k < 4; ++k) bar[tid * 4 + k] = 0;
    return;
  }
  __shared__ int cnt[5];
  if (tid < 5) cnt[tid] = 0;
  __syncthreads();
  const unsigned char* p = (const unsigned char*)mask;
  int l0 = 0, l1 = 0, l2 = 0, l3 = 0, l4 = 0;
  const int base = tid * 64;
  for (int k = 0; k < 64; ++k) {
    const int off = base + k;
    if (p[off]) {
      const int m4 = off & 3;
      if (m4 == 1) l1++;
      else if (m4 == 2) l2++;
      else if (m4 == 3) l3++;
      else if ((off & 7) == 4) l4++;
      else l0++;
    }
  }
  if (l0) atomicAdd(&cnt[0], 1);
  if (l1) atomicAdd(&cnt[1], 1);
  if (l2) atomicAdd(&cnt[2], 1);
  if (l3) atomicAdd(&cnt[3], 1);
  if (l4) atomicAdd(&cnt[4], 1);
  __syncthreads();
  if (tid == 0) {
    int f;
    if (cnt[1]) f = 1;
    else if (cnt[2] || cnt[3]) f = 2;
    else if (cnt[4]) f = 0;
    else if (cnt[0]) f = 3;
    else f = 1;
    *flag = f;
  }
}

// ---------------------------------------------------------------------------
// prep_gemm (unchanged from R2, known-good): out fp16, M=32768, K=256, N=128.
// MODE 0: x = out_emb + pos,       out = fp16((x @ W) * w_aff)
// MODE 1: x = mask ? pad : in_emb, out = fp16( x @ W )
// ---------------------------------------------------------------------------
template <int MODE>
__global__ __launch_bounds__(256) void prep_gemm(
    const float* __restrict__ X, const float* __restrict__ extra,
    const void* __restrict__ maskp, const int* __restrict__ flagp,
    const float* __restrict__ W, const float* __restrict__ w_aff,
    half_t* __restrict__ out) {
  __shared__ float Xs[64][65];
  __shared__ alignas(16) float Ws[64][CE];
  const int tid = threadIdx.x;
  const int row0 = blockIdx.x * 64;
  const int tx = tid & 15, ty = tid >> 4;
  const int flag = (MODE == 1) ? *flagp : 0;
  float acc[4][8];
#pragma unroll
  for (int a = 0; a < 4; ++a)
#pragma unroll
    for (int c = 0; c < 8; ++c) acc[a][c] = 0.0f;

  for (int kc = 0; kc < CD; kc += 64) {
    {
      const int lk = tid & 15;
      const int rp = tid >> 4;
#pragma unroll
      for (int pass = 0; pass < 4; ++pass) {
        const int r = pass * 16 + rp;
        const int row = row0 + r;
        const int i = row & (CN - 1);
        const int d = kc + lk * 4;
        float4 x4;
        if (MODE == 0) {
          x4 = *(const float4*)&X[(size_t)row * CD + d];
          const float4 p4 = *(const float4*)&extra[(size_t)i * CD + d];
          x4.x += p4.x; x4.y += p4.y; x4.z += p4.z; x4.w += p4.w;
        } else {
          bool m;
          if (flag == 1)      m = ((const unsigned char*)maskp)[row] != 0;
          else if (flag == 2) m = ((const float*)maskp)[row] != 0.0f;
          else if (flag == 3) m = ((const long long*)maskp)[row] != 0;
          else                m = ((const int*)maskp)[row] != 0;
          if (m) x4 = *(const float4*)&extra[d];
          else   x4 = *(const float4*)&X[(size_t)row * CD + d];
        }
        Xs[r][lk * 4 + 0] = x4.x; Xs[r][lk * 4 + 1] = x4.y;
        Xs[r][lk * 4 + 2] = x4.z; Xs[r][lk * 4 + 3] = x4.w;
      }
    }
    {
      const int cv = tid & 31;
      const int kr = tid >> 5;
#pragma unroll
      for (int pass = 0; pass < 8; ++pass) {
        const int kk = pass * 8 + kr;
        *(float4*)&Ws[kk][cv * 4] = *(const float4*)&W[(size_t)(kc + kk) * CE + cv * 4];
      }
    }
    __syncthreads();
#pragma unroll 4
    for (int kk = 0; kk < 64; ++kk) {
      float xa[4];
#pragma unroll
      for (int a = 0; a < 4; ++a) xa[a] = Xs[ty * 4 + a][kk];
      const float4 wb0 = *(const float4*)&Ws[kk][tx * 8];
      const float4 wb1 = *(const float4*)&Ws[kk][tx * 8 + 4];
      const float wb[8] = {wb0.x, wb0.y, wb0.z, wb0.w, wb1.x, wb1.y, wb1.z, wb1.w};
#pragma unroll
      for (int a = 0; a < 4; ++a)
#pragma unroll
        for (int c = 0; c < 8; ++c) acc[a][c] += xa[a] * wb[c];
    }
    __syncthreads();
  }
  float wa[8];
  if (MODE == 0) {
#pragma unroll
    for (int c = 0; c < 8; ++c) wa[c] = w_aff[tx * 8 + c];
  }
#pragma unroll
  for (int a = 0; a < 4; ++a) {
    const int row = row0 + ty * 4 + a;
    v8h hv;
#pragma unroll
    for (int c = 0; c < 8; ++c) {
      const float o = (MODE == 0) ? acc[a][c] * wa[c] : acc[a][c];
      hv[c] = (half_t)o;
    }
    *(v8h*)&out[(size_t)row * CE + tx * 8] = hv;
  }
}

// ---------------------------------------------------------------------------
// Per-batch barrier among the 4 slab-blocks of a batch (grid = 256 = CU count,
// all blocks resident). Proven in R2.
// ---------------------------------------------------------------------------
__device__ __forceinline__ void batch_barrier(int* __restrict__ bar, int b, int gen4) {
  __syncthreads();
  if (threadIdx.x == 0) {
    __hip_atomic_fetch_add(&bar[b * 32], 1, __ATOMIC_RELEASE, __HIP_MEMORY_SCOPE_AGENT);
    while (__hip_atomic_load(&bar[b * 32], __ATOMIC_ACQUIRE, __HIP_MEMORY_SCOPE_AGENT) < gen4)
      __builtin_amdgcn_s_sleep(2);
  }
  __syncthreads();
}

// ---------------------------------------------------------------------------
// fused_reg: block = (batch b, 128-row slab), 512 threads = 8 waves.
// Wave wv owns rows [wv*16, wv*16+16); lane (q=ln>>4, l=ln&15).
// E slab lives in REGISTERS as packed fp16 in MFMA C-fragment layout:
//   eh[ct][g]  <->  E[row = wv*16 + q*4 + g][col = ct*16 + l],  ct = 0..31.
// Stored value is exp(aff + b_aff - ln16) — global 2^-4 scale cancels exactly
// in both softmax normalizations (K invariant), and keeps fp16 from overflow.
// GEMM epilogue fuses the init row/col sums. 20 sinkhorn iters = register
// sweeps + shfl reductions + 4KB cross-slab exchange per iter.
// ---------------------------------------------------------------------------
__global__ __launch_bounds__(512) void fused_reg(
    const half_t* __restrict__ A_h, const half_t* __restrict__ B_h,
    const float* __restrict__ baff, float* __restrict__ P,
    float* __restrict__ part, int* __restrict__ bar) {
  __shared__ float comb[8][2][512];      // per-wave column partials (32 KB)
  __shared__ float w1_l[512];            // 0.5 * v * csinv
  __shared__ float w2_l[512];            // v
  __shared__ float csinv_l[512];
  __shared__ float rinv_l[128];

  const int tid = threadIdx.x;
  const int wv = tid >> 6, ln = tid & 63;
  const int q = ln >> 4, l = ln & 15;
  const int b = blockIdx.x & 63;
  const int slab = blockIdx.x >> 6;
  const int i0 = slab * 128;
  const float bbs = *baff - 2.7725887f;   // fold 2^-4 scale into exp

  // ---- GEMM: 16 rows x 512 cols per wave, K=128, fp16 MFMA + fused init ----
  v8h af[4];
  {
    const half_t* Arow = &A_h[((size_t)b * CN + i0 + wv * 16 + l) * CE];
#pragma unroll
    for (int ki = 0; ki < 4; ++ki)
      af[ki] = *(const v8h*)&Arow[ki * 32 + q * 8];
  }
  v4h eh[32];
  float d[4] = {0.0f, 0.0f, 0.0f, 0.0f};   // row-sum accumulators
  const half_t* Bbase = &B_h[(size_t)b * CN * CE];
#pragma unroll
  for (int ct = 0; ct < 32; ++ct) {
    v8h bf[4];
    const half_t* Brow = &Bbase[(size_t)(ct * 16 + l) * CE];
#pragma unroll
    for (int ki = 0; ki < 4; ++ki)
      bf[ki] = *(const v8h*)&Brow[ki * 32 + q * 8];
    v4f acc = {};
#pragma unroll
    for (int ki = 0; ki < 4; ++ki)
      acc = __builtin_amdgcn_mfma_f32_16x16x32_f16(af[ki], bf[ki], acc, 0, 0, 0);
    float colsum = 0.0f;
    v4h ev;
#pragma unroll
    for (int g = 0; g < 4; ++g) {
      const float e = __expf(acc[g] + bbs);
      d[g] += e;
      colsum += e;
      ev[g] = (half_t)e;
    }
    eh[ct] = ev;
    colsum += __shfl_xor(colsum, 16);
    colsum += __shfl_xor(colsum, 32);
    if (ln < 16) comb[wv][0][ct * 16 + ln] = colsum;
  }
  // row sums -> rinv
#pragma unroll
  for (int g = 0; g < 4; ++g) {
#pragma unroll
    for (int m = 1; m < 16; m <<= 1) d[g] += __shfl_xor(d[g], m);
  }
  if (l == 0) {
#pragma unroll
    for (int g = 0; g < 4; ++g) rinv_l[wv * 16 + q * 4 + g] = 1.0f / d[g];
  }
  __syncthreads();

  // ---- init exchange: column sums -> csinv, w init (v = 1) ----
  int gen = 0;
  {
    float S = 0.0f;
#pragma unroll
    for (int w = 0; w < 8; ++w) S += comb[w][0][tid];
    part[(((size_t)(0 * 64 + b) * 4 + slab) * 2 + 0) * 512 + tid] = S;
    ++gen;
    batch_barrier(bar, b, 4 * gen);
    float T = 0.0f;
#pragma unroll
    for (int sl = 0; sl < 4; ++sl)
      T += part[(((size_t)(0 * 64 + b) * 4 + sl) * 2 + 0) * 512 + tid];
    const float ci = 1.0f / T;
    csinv_l[tid] = ci;
    w1_l[tid] = 0.5f * ci;
    w2_l[tid] = 1.0f;
  }
  float rv[4];
#pragma unroll
  for (int g = 0; g < 4; ++g) rv[g] = rinv_l[wv * 16 + q * 4 + g];

  // ---- 20 sinkhorn iterations ----
  float u_[4], uri[4];
  for (int t = 0; t < CIT; ++t) {
    __syncthreads();   // w1_l/w2_l ready
    // pass 1: row dots -> u
    float p1[4] = {0, 0, 0, 0}, p2[4] = {0, 0, 0, 0};
#pragma unroll
    for (int ct = 0; ct < 32; ++ct) {
      const float w1v = w1_l[ct * 16 + l];
      const float w2v = w2_l[ct * 16 + l];
      const v4h ev = eh[ct];
#pragma unroll
      for (int g = 0; g < 4; ++g) {
        const float e = (float)ev[g];
        p1[g] = fmaf(e, w1v, p1[g]);
        p2[g] = fmaf(e, w2v, p2[g]);
      }
    }
#pragma unroll
    for (int g = 0; g < 4; ++g) {
#pragma unroll
      for (int m = 1; m < 16; m <<= 1) {
        p1[g] += __shfl_xor(p1[g], m);
        p2[g] += __shfl_xor(p2[g], m);
      }
      u_[g] = 1.0f / (p1[g] + 0.5f * rv[g] * p2[g]);
      uri[g] = u_[g] * rv[g];
    }
    // pass 2: column partials
#pragma unroll
    for (int ct = 0; ct < 32; ++ct) {
      const v4h ev = eh[ct];
      float s1 = 0.0f, s2 = 0.0f;
#pragma unroll
      for (int g = 0; g < 4; ++g) {
        const float e = (float)ev[g];
        s1 = fmaf(e, u_[g], s1);
        s2 = fmaf(e, uri[g], s2);
      }
      s1 += __shfl_xor(s1, 16); s1 += __shfl_xor(s1, 32);
      s2 += __shfl_xor(s2, 16); s2 += __shfl_xor(s2, 32);
      if (ln < 16) {
        comb[wv][0][ct * 16 + ln] = s1;
        comb[wv][1][ct * 16 + ln] = s2;
      }
    }
    __syncthreads();
    // cross-wave + cross-slab exchange; thread tid owns column tid
    float S1 = 0.0f, S2 = 0.0f;
#pragma unroll
    for (int w = 0; w < 8; ++w) {
      S1 += comb[w][0][tid];
      S2 += comb[w][1][tid];
    }
    const int slot = gen & 1;
    part[(((size_t)(slot * 64 + b) * 4 + slab) * 2 + 0) * 512 + tid] = S1;
    part[(((size_t)(slot * 64 + b) * 4 + slab) * 2 + 1) * 512 + tid] = S2;
    ++gen;
    batch_barrier(bar, b, 4 * gen);
    float T1 = 0.0f, T2 = 0.0f;
#pragma unroll
    for (int sl = 0; sl < 4; ++sl) {
      T1 += part[(((size_t)(slot * 64 + b) * 4 + sl) * 2 + 0) * 512 + tid];
      T2 += part[(((size_t)(slot * 64 + b) * 4 + sl) * 2 + 1) * 512 + tid];
    }
    const float ci = csinv_l[tid];
    const float vv = 1.0f / (0.5f * fmaf(ci, T1, T2));
    w1_l[tid] = 0.5f * vv * ci;
    w2_l[tid] = vv;
  }

  // ---- finalize: P = E * u_i * v_j * (0.5*csinv_j + 0.5*rinv_i) ----
  __syncthreads();
  float* Pb = &P[((size_t)b * CN + i0 + wv * 16 + q * 4) * CN];
#pragma unroll
  for (int ct = 0; ct < 32; ++ct) {
    const float c1 = w1_l[ct * 16 + l];
    const float c2 = 0.5f * w2_l[ct * 16 + l];
    const v4h ev = eh[ct];
#pragma unroll
    for (int g = 0; g < 4; ++g) {
      const float e = (float)ev[g];
      Pb[(size_t)g * CN + ct * 16 + l] = e * fmaf(u_[g], c1, uri[g] * c2);
    }
  }
}

// ---------------------------------------------------------------------------
extern "C" void kernel_launch(void* const* d_in, const int* in_sizes, int n_in,
                              void* d_out, int out_size, void* d_ws, size_t ws_size,
                              hipStream_t stream) {
  const float* in_emb  = (const float*)d_in[0];
  const void*  mask    = d_in[1];
  const float* out_emb = (const float*)d_in[2];
  const float* pad     = (const float*)d_in[3];
  const float* pos     = (const float*)d_in[4];
  const float* W_a     = (const float*)d_in[5];
  const float* W_b     = (const float*)d_in[6];
  const float* w_aff   = (const float*)d_in[7];
  const float* b_aff   = (const float*)d_in[8];
  float* P = (float*)d_out;

  char* ws = (char*)d_ws;
  half_t* A_h  = (half_t*)ws;                                    // 8 MB
  half_t* Bm_h = (half_t*)(ws + (size_t)8 * 1024 * 1024);        // 8 MB
  float*  part = (float*)(ws + (size_t)16 * 1024 * 1024);        // 2 MB
  int*    bar  = (int*)(ws + (size_t)18 * 1024 * 1024);          // 8 KB
  int*    flag = (int*)(ws + (size_t)18 * 1024 * 1024 + 8192);

  k0_init<<<dim3(2), dim3(512), 0, stream>>>(mask, bar, flag);
  prep_gemm<0><<<dim3(CB * CN / 64), dim3(256), 0, stream>>>(
      out_emb, pos, nullptr, flag, W_a, w_aff, A_h);
  prep_gemm<1><<<dim3(CB * CN / 64), dim3(256), 0, stream>>>(
      in_emb, pad, mask, flag, W_b, nullptr, Bm_h);
  fused_reg<<<dim3(256), dim3(512), 0, stream>>>(A_h, Bm_h, b_aff, P, part, bar);
}